// Round 5
// baseline (519.520 us; speedup 1.0000x reference)
//
#include <hip/hip_runtime.h>
#include <hip/hip_bf16.h>
#include <hip/hip_cooperative_groups.h>
#include <math.h>

namespace cg = cooperative_groups;

// Problem constants (B=2, L=1024, D=768, H=12, DH=64, LAT=512)
#define D_MODEL 768
#define NHEAD   12
#define LATD    512
#define BATCH   2
#define SEQ     1024
#define NROWS   (BATCH*SEQ)          // 2048
#define NCHUNK  (SEQ/64)             // 16
#define NBH     (BATCH*NHEAD)        // 24
#define NFUSE   3200                 // qkv 2304 + params pad 128 + gate 768
#define PQ      72                   // LDS ushort pitch (144 B rows, 16B-aligned frags)
#define NATTN   (NBH*NCHUNK)         // 384 cooperative blocks

using short8 = __attribute__((ext_vector_type(8))) short;
using f32x4  = __attribute__((ext_vector_type(4))) float;

__device__ __forceinline__ float sigf(float x){ return 1.f/(1.f+expf(-x)); }
__device__ __forceinline__ float decay_of(float hd){
  float d = 0.3f + 0.65f*sigf(hd);
  return fminf(fmaxf(d, 1e-5f), 0.999f);
}
__device__ __forceinline__ unsigned short f2b(float f){
  __hip_bfloat16 h = __float2bfloat16(f);
  return *reinterpret_cast<unsigned short*>(&h);
}
__device__ __forceinline__ float bf2f(unsigned short u){
  unsigned int x = ((unsigned int)u) << 16;
  return __uint_as_float(x);
}
__device__ __forceinline__ void async16(const unsigned short* g, unsigned short* l){
  __builtin_amdgcn_global_load_lds((const __attribute__((address_space(1))) void*)g,
                                   (__attribute__((address_space(3))) void*)l, 16, 0, 0);
}

// ------- weight converts/transposes + xn rmsnorm, one launch (2688 blocks) -------
__global__ __launch_bounds__(256) void k_cvt_all(const float* __restrict__ wc,
    const float* __restrict__ wq, const float* __restrict__ wr,
    const float* __restrict__ wg, const float* __restrict__ wp,
    const float* __restrict__ x, const float* __restrict__ wln,
    unsigned short* __restrict__ wtc, unsigned short* __restrict__ wtq,
    unsigned short* __restrict__ wtg, unsigned short* __restrict__ wtp,
    unsigned short* __restrict__ xn)
{
  __shared__ unsigned short tile[64][65];
  __shared__ float red[4];
  int blk = blockIdx.x, t = threadIdx.x;
  if (blk >= 640){
    // rmsnorm(x) -> bf16 xn, one block per row
    int row = blk - 640;
    const float* xr = x + (size_t)row*D_MODEL;
    float v0 = xr[t], v1 = xr[t+256], v2 = xr[t+512];
    float s = v0*v0 + v1*v1 + v2*v2;
    #pragma unroll
    for (int off=32; off; off>>=1) s += __shfl_xor(s, off, 64);
    if ((t & 63) == 0) red[t>>6] = s;
    __syncthreads();
    s = red[0]+red[1]+red[2]+red[3];
    float sc = rsqrtf(s*(1.f/(float)D_MODEL) + 1e-6f);
    unsigned short* yr = xn + (size_t)row*D_MODEL;
    yr[t]     = f2b(v0*sc*wln[t]);
    yr[t+256] = f2b(v1*sc*wln[t+256]);
    yr[t+512] = f2b(v2*sc*wln[t+512]);
    return;
  }
  if (blk >= 624){
    // w_reso [512][48] -> wtq rows 2304..2431 (zero-pad 2352..2431)
    int i = blk - 624;                    // 0..15
    #pragma unroll
    for (int j=0;j<16;j++){
      int e = i*4096 + t + j*256;         // 0..65535
      int n = 2304 + (e >> 9), k = e & 511;
      float v = (n < 2352) ? wr[(size_t)k*48 + (n-2304)] : 0.f;
      wtq[(size_t)n*512 + k] = f2b(v);
    }
    return;
  }
  const float* W; unsigned short* WT; int K, N, bx, by;
  if (blk < 96){ W=wc; WT=wtc; K=768; N=512; bx=blk&7; by=blk>>3; }
  else if (blk < 384){ int i=blk-96;  W=wq; WT=wtq; K=512; N=2304; bx=i%36; by=i/36; }
  else if (blk < 480){ int i=blk-384; W=wg; WT=wtg; K=512; N=768;  bx=i%12; by=i/12; }
  else               { int i=blk-480; W=wp; WT=wtp; K=768; N=768;  bx=i%12; by=i/12; }
  int k0 = by*64, n0 = bx*64, cr = t >> 6, cc = t & 63;
  #pragma unroll
  for (int i=0;i<16;i++){
    int r = cr + i*4;
    tile[r][cc] = f2b(W[(size_t)(k0+r)*N + n0 + cc]);
  }
  __syncthreads();
  #pragma unroll
  for (int i=0;i<16;i++){
    int nn = cr + i*4;
    WT[(size_t)(n0+nn)*K + k0 + cc] = tile[cc][nn];
  }
}

// ------- bf16 MFMA GEMM, BM=128 BN=64: C = A[M,K] @ BT[N,K]^T -------------------
// act: 1 = silu (bf16 out Cb), 2 = multiply by bf16 aux (fp32 out Cf)
__global__ __launch_bounds__(256) void k_mfma_gemm(const unsigned short* __restrict__ A,
    const unsigned short* __restrict__ BT, float* __restrict__ Cf,
    unsigned short* __restrict__ Cb, const unsigned short* __restrict__ auxb,
    int M, int N, int K, int act)
{
  __shared__ unsigned short As[128*64];
  __shared__ unsigned short Bs[64*64];
  int tid = threadIdx.x;
  int w = tid >> 6, lane = tid & 63;
  int wm = (w >> 1)*64, wn = (w & 1)*32;
  int m16 = lane & 15, quad = lane >> 4;
  int bm = blockIdx.y*128, bn = blockIdx.x*64;

  f32x4 acc[4][2];
  #pragma unroll
  for (int i=0;i<4;i++)
    #pragma unroll
    for (int j=0;j<2;j++) acc[i][j] = (f32x4){0.f,0.f,0.f,0.f};

  for (int kk = 0; kk < K; kk += 64){
    #pragma unroll
    for (int i=0;i<4;i++){
      int g = (w*4 + i)*64 + lane;
      int m = g >> 3, c = (g & 7) ^ (m & 7);
      async16(A + (size_t)(bm+m)*K + kk + c*8, As + (w*4+i)*512);
    }
    #pragma unroll
    for (int i=0;i<2;i++){
      int g = (w*2 + i)*64 + lane;
      int m = g >> 3, c = (g & 7) ^ (m & 7);
      async16(BT + (size_t)(bn+m)*K + kk + c*8, Bs + (w*2+i)*512);
    }
    __syncthreads();
    #pragma unroll
    for (int s=0;s<2;s++){
      short8 af[4], bf[2];
      #pragma unroll
      for (int mt=0;mt<4;mt++){
        int m = wm + mt*16 + m16;
        int idx = m*8 + ((s*4 + quad) ^ (m & 7));
        af[mt] = *(const short8*)(As + idx*8);
      }
      #pragma unroll
      for (int nt=0;nt<2;nt++){
        int n = wn + nt*16 + m16;
        int idx = n*8 + ((s*4 + quad) ^ (n & 7));
        bf[nt] = *(const short8*)(Bs + idx*8);
      }
      #pragma unroll
      for (int mt=0;mt<4;mt++)
        #pragma unroll
        for (int nt=0;nt<2;nt++)
          acc[mt][nt] = __builtin_amdgcn_mfma_f32_16x16x32_bf16(af[mt], bf[nt], acc[mt][nt], 0, 0, 0);
    }
    __syncthreads();
  }
  #pragma unroll
  for (int mt=0;mt<4;mt++){
    #pragma unroll
    for (int r=0;r<4;r++){
      int row = bm + wm + mt*16 + quad*4 + r;
      #pragma unroll
      for (int nt=0;nt<2;nt++){
        int col = bn + wn + nt*16 + m16;
        float v = acc[mt][nt][r];
        if (act == 1) v = v/(1.f + __expf(-v));
        else if (act == 2) v *= bf2f(auxb[(size_t)row*N + col]);
        if (Cf) Cf[(size_t)row*N + col] = v;
        if (Cb) Cb[(size_t)row*N + col] = f2b(v);
      }
    }
  }
}

// ------- fused GEMM: [qkv | params | gate] = latent @ BT (N=3200) ----------------
// Epilogue: per-head rmsnorm + rope + elu+1 (q/k), v copy, coef (params), silu gate.
__global__ __launch_bounds__(256) void k_gemm_fused(const unsigned short* __restrict__ A,
    const unsigned short* __restrict__ BT, const float* __restrict__ w_qn,
    const float* __restrict__ w_kn, const float* __restrict__ hdec,
    const float* __restrict__ temp, unsigned short* __restrict__ qf,
    unsigned short* __restrict__ kf, unsigned short* __restrict__ vf,
    float* __restrict__ cKV, float* __restrict__ cG,
    unsigned short* __restrict__ gateb)
{
  __shared__ unsigned short As[128*64];
  __shared__ unsigned short Bs[128*64];
  const int K = LATD;
  int tid = threadIdx.x;
  int w = tid >> 6, lane = tid & 63;
  int wm = (w >> 1)*64, wn = (w & 1)*64;
  int m16 = lane & 15, quad = lane >> 4;
  int bm = blockIdx.y*128, bn = blockIdx.x*128;

  f32x4 acc[4][4];
  #pragma unroll
  for (int i=0;i<4;i++)
    #pragma unroll
    for (int j=0;j<4;j++) acc[i][j] = (f32x4){0.f,0.f,0.f,0.f};

  for (int kk = 0; kk < K; kk += 64){
    #pragma unroll
    for (int i=0;i<4;i++){
      int g = (w*4 + i)*64 + lane;
      int m = g >> 3, c = (g & 7) ^ (m & 7);
      async16(A  + (size_t)(bm+m)*K + kk + c*8, As + (w*4+i)*512);
      async16(BT + (size_t)(bn+m)*K + kk + c*8, Bs + (w*4+i)*512);
    }
    __syncthreads();
    #pragma unroll
    for (int s=0;s<2;s++){
      short8 af[4], bf[4];
      #pragma unroll
      for (int mt=0;mt<4;mt++){
        int m = wm + mt*16 + m16;
        int idx = m*8 + ((s*4 + quad) ^ (m & 7));
        af[mt] = *(const short8*)(As + idx*8);
      }
      #pragma unroll
      for (int nt=0;nt<4;nt++){
        int n = wn + nt*16 + m16;
        int idx = n*8 + ((s*4 + quad) ^ (n & 7));
        bf[nt] = *(const short8*)(Bs + idx*8);
      }
      #pragma unroll
      for (int mt=0;mt<4;mt++)
        #pragma unroll
        for (int nt=0;nt<4;nt++)
          acc[mt][nt] = __builtin_amdgcn_mfma_f32_16x16x32_bf16(af[mt], bf[nt], acc[mt][nt], 0, 0, 0);
    }
    __syncthreads();
  }

  int colbase = bn + wn;                // 64-aligned; wave owns cols [colbase, colbase+64)
  if (colbase < 2304){
    int sec = colbase >= 1536 ? 2 : (colbase >= 768 ? 1 : 0);   // 0=q 1=k 2=v
    int h = (colbase - sec*768) >> 6;
    if (sec == 2){
      #pragma unroll
      for (int mt=0;mt<4;mt++)
        #pragma unroll
        for (int r=0;r<4;r++){
          int row = bm + wm + mt*16 + quad*4 + r;
          int b = row >> 10, t = row & 1023;
          size_t ob = (((size_t)(b*NHEAD+h))*SEQ + t)*64;
          #pragma unroll
          for (int nt=0;nt<4;nt++)
            vf[ob + nt*16 + m16] = f2b(acc[mt][nt][r]);
        }
    } else {
      const float* wnp = sec ? w_kn : w_qn;
      unsigned short* of = sec ? kf : qf;
      float wv4[4];
      #pragma unroll
      for (int nt=0;nt<4;nt++) wv4[nt] = wnp[nt*16 + m16];
      float inv0 = exp2f(-(float)m16*(1.f/32.f)*13.28771237954945f);  // 10000^{-m16/32}
      float inv1 = inv0 * 0.01f;                                      // * 10000^{-16/32}
      #pragma unroll
      for (int mt=0;mt<4;mt++)
        #pragma unroll
        for (int r=0;r<4;r++){
          int row = bm + wm + mt*16 + quad*4 + r;
          int b = row >> 10, t = row & 1023;
          float s = 0.f;
          #pragma unroll
          for (int nt=0;nt<4;nt++) s += acc[mt][nt][r]*acc[mt][nt][r];
          s += __shfl_xor(s, 1, 64); s += __shfl_xor(s, 2, 64);
          s += __shfl_xor(s, 4, 64); s += __shfl_xor(s, 8, 64);
          float rs = rsqrtf(s*(1.f/64.f) + 1e-6f);
          float qv[4];
          #pragma unroll
          for (int nt=0;nt<4;nt++) qv[nt] = acc[mt][nt][r]*rs*wv4[nt];
          float s0,c0,s1,c1;
          __sincosf((float)t*inv0, &s0, &c0);
          __sincosf((float)t*inv1, &s1, &c1);
          size_t ob = (((size_t)(b*NHEAD+h))*SEQ + t)*64;
          #pragma unroll
          for (int nt=0;nt<4;nt++){
            float rot = (nt < 2) ? -qv[nt+2] : qv[nt-2];
            float cs = (nt & 1) ? c1 : c0, sn = (nt & 1) ? s1 : s0;
            float val = qv[nt]*cs + rot*sn;
            val = (val > 0.f) ? val + 1.f : __expf(val);
            of[ob + nt*16 + m16] = f2b(val);
          }
        }
    }
  } else if (colbase == 2304){
    // resonance params -> coefficients (heads h = p>>2, param pi = p&3 in lane m16)
    float temp0 = temp[0];
    #pragma unroll
    for (int mt=0;mt<4;mt++)
      #pragma unroll
      for (int r=0;r<4;r++){
        int row = bm + wm + mt*16 + quad*4 + r;
        int b = row >> 10, t = row & 1023;
        #pragma unroll
        for (int nt=0;nt<3;nt++){
          int p = nt*16 + m16, h2 = p >> 2, pi = p & 3;
          float v  = acc[mt][nt][r];
          float v1 = __shfl_xor(v, 1, 64);
          float v2 = __shfl_xor(v, 2, 64);
          float v3 = __shfl_xor(v, 3, 64);
          if (pi == 0){
            float sa = sigf(v);
            float sp = sigf(v1)*3.14159265358979323846f;
            float ca = sigf(v2);
            float cp = sigf(v3)*3.14159265358979323846f;
            float z = sa*ca*cosf(sp - cp)*temp0;
            float gate = fminf(fmaxf(sigf(z)*1.2f - 0.1f, 0.05f), 0.95f);
            float dd = decay_of(hdec[h2]);
            float df = expf((float)(t+1)*logf(dd));
            float g = df/(df + 1e-8f);
            int ci = (b*NHEAD + h2)*SEQ + t;
            cKV[ci] = g*gate*(1.f - dd);
            cG[ci]  = 1.f/gate;
          }
        }
      }
  } else if (colbase >= 2432){
    // out-gate: silu -> bf16
    #pragma unroll
    for (int mt=0;mt<4;mt++)
      #pragma unroll
      for (int r=0;r<4;r++){
        int row = bm + wm + mt*16 + quad*4 + r;
        #pragma unroll
        for (int nt=0;nt<4;nt++){
          int gc = colbase + nt*16 + m16 - 2432;
          float v = acc[mt][nt][r];
          v = v/(1.f + __expf(-v));
          gateb[(size_t)row*D_MODEL + gc] = f2b(v);
        }
      }
  }
}

// ------- cooperative attention megakernel: intra -> scan -> cross -> memnorm -----
__global__ __launch_bounds__(256) void k_attn(
    const unsigned short* __restrict__ qf, const unsigned short* __restrict__ kf,
    const unsigned short* __restrict__ vf, const float* __restrict__ cKVb,
    const float* __restrict__ cGb, const float* __restrict__ hdec,
    float* __restrict__ numb, float* __restrict__ denb,
    float* __restrict__ Pb, float* __restrict__ zPb,
    unsigned short* __restrict__ Sprev, unsigned short* __restrict__ zprev,
    float* __restrict__ attn, const float* __restrict__ w_mn,
    unsigned short* __restrict__ memn)
{
  cg::grid_group grid = cg::this_grid();
  __shared__ __align__(16) unsigned short sm_u[336*PQ];   // 48384 B, phase-aliased
  __shared__ float cn[64], cps[64], den_sm[64], red[4];
  int bid = blockIdx.x;
  int chunk = bid & 15, bh = bid >> 4, h = bh % NHEAD, b = bh / NHEAD;
  int tid = threadIdx.x, w = tid >> 6, lane = tid & 63;
  int m16 = lane & 15, quad = lane >> 4;
  size_t base = ((size_t)bh*SEQ + chunk*64)*64;
  float d = decay_of(hdec[h]);
  float l2d = log2f(d);

  // ================= phase A: intra-chunk =================
  {
    unsigned short* Qb  = sm_u;             // [t][k]
    unsigned short* Kb  = sm_u + 64*PQ;     // [s][d]
    unsigned short* KtS = sm_u + 128*PQ;    // [d][s]
    unsigned short* Wb  = sm_u + 192*PQ;    // [t][s]
    unsigned short* Vt  = sm_u + 256*PQ;    // [e][s], row64 = invgate, 65..79 = 0

    if (tid < 64){
      float c = cKVb[bh*SEQ + chunk*64 + tid];
      float pw = exp2f((float)(63 - tid)*l2d);
      cn[tid] = c;
      cps[tid] = c*pw;
      Vt[64*PQ + tid] = f2b(cGb[bh*SEQ + chunk*64 + tid]);
    }
    for (int i = tid; i < 15*PQ; i += 256) Vt[65*PQ + i] = 0;
    __syncthreads();   // cps ready for KtS staging

    #pragma unroll
    for (int i=0;i<2;i++){
      int g = tid + i*256;
      int r = g >> 3, c8 = (g & 7)*8;
      *(short8*)(Qb + r*PQ + c8) = *(const short8*)(qf + base + r*64 + c8);
      *(short8*)(Kb + r*PQ + c8) = *(const short8*)(kf + base + r*64 + c8);
    }
    {
      int s = tid & 63;
      float cpss = cps[s];
      #pragma unroll
      for (int i=0;i<2;i++){
        int c8 = ((tid >> 6) + i*4)*8;
        short8 vv = *(const short8*)(vf + base + s*64 + c8);
        short8 kk = *(const short8*)(kf + base + s*64 + c8);
        #pragma unroll
        for (int j=0;j<8;j++){
          Vt[(c8+j)*PQ + s] = ((unsigned short*)&vv)[j];
          KtS[(c8+j)*PQ + s] = f2b(bf2f(((unsigned short*)&kk)[j])*cpss);
        }
      }
    }
    __syncthreads();

    int trow = w*16 + quad*4;
    for (int stile=0; stile<4; stile++){
      if (stile > w){
        #pragma unroll
        for (int r=0;r<4;r++) Wb[(trow+r)*PQ + stile*16 + m16] = 0;
        continue;
      }
      f32x4 acc = (f32x4){0.f,0.f,0.f,0.f};
      #pragma unroll
      for (int ks=0;ks<2;ks++){
        short8 a = *(const short8*)(Qb + (w*16 + m16)*PQ + ks*32 + quad*8);
        short8 bv = *(const short8*)(Kb + (stile*16 + m16)*PQ + ks*32 + quad*8);
        acc = __builtin_amdgcn_mfma_f32_16x16x32_bf16(a, bv, acc, 0, 0, 0);
      }
      int s = stile*16 + m16;
      float cns = cn[s];
      #pragma unroll
      for (int r=0;r<4;r++){
        int t = trow + r;
        float wv = 0.f;
        if (s <= t) wv = acc[r]*exp2f((float)(t-s)*l2d)*cns;
        Wb[t*PQ + s] = f2b(wv);
      }
    }
    __syncthreads();

    {
      f32x4 acc[5];
      #pragma unroll
      for (int et=0;et<5;et++) acc[et] = (f32x4){0.f,0.f,0.f,0.f};
      #pragma unroll
      for (int et=0;et<5;et++)
        #pragma unroll
        for (int ks=0;ks<2;ks++){
          short8 a = *(const short8*)(Wb + (w*16 + m16)*PQ + ks*32 + quad*8);
          short8 bv = *(const short8*)(Vt + (et*16 + m16)*PQ + ks*32 + quad*8);
          acc[et] = __builtin_amdgcn_mfma_f32_16x16x32_bf16(a, bv, acc[et], 0, 0, 0);
        }
      #pragma unroll
      for (int et=0;et<4;et++)
        #pragma unroll
        for (int r=0;r<4;r++)
          numb[base + (size_t)(trow+r)*64 + et*16 + m16] = acc[et][r];
      if (m16 == 0){
        #pragma unroll
        for (int r=0;r<4;r++)
          denb[bh*SEQ + chunk*64 + trow + r] = acc[4][r];
      }
    }
    {
      #pragma unroll
      for (int j=0;j<5;j++){
        int tIdx = w + 4*j;
        int et = tIdx >> 2, dt = tIdx & 3;
        f32x4 acc = (f32x4){0.f,0.f,0.f,0.f};
        #pragma unroll
        for (int ks=0;ks<2;ks++){
          short8 a = *(const short8*)(Vt  + (et*16 + m16)*PQ + ks*32 + quad*8);
          short8 bv = *(const short8*)(KtS + (dt*16 + m16)*PQ + ks*32 + quad*8);
          acc = __builtin_amdgcn_mfma_f32_16x16x32_bf16(a, bv, acc, 0, 0, 0);
        }
        if (et < 4){
          #pragma unroll
          for (int r=0;r<4;r++)
            Pb[(size_t)bid*4096 + (et*16 + quad*4 + r)*64 + dt*16 + m16] = acc[r];
        } else {
          if (quad == 0) zPb[bid*64 + dt*16 + m16] = acc[0];
        }
      }
    }
  }
  __threadfence();
  grid.sync();

  // ================= phase B: chunk scan (blocks 0..95) =================
  if (bid < 96){
    int bh2 = bid >> 2, part = bid & 3, h2 = bh2 % NHEAD;
    float d2 = decay_of(hdec[h2]);
    float d64 = exp2f(64.f*log2f(d2));
    int idx = part*1024 + tid*4;
    float4 S = make_float4(0.f,0.f,0.f,0.f);
    for (int c=0;c<NCHUNK;c++){
      size_t off = ((size_t)bh2*NCHUNK + c)*4096 + idx;
      unsigned int lo = (unsigned int)f2b(S.x) | ((unsigned int)f2b(S.y) << 16);
      unsigned int hi = (unsigned int)f2b(S.z) | ((unsigned int)f2b(S.w) << 16);
      *(uint2*)(Sprev + off) = make_uint2(lo, hi);
      float4 p = *(const float4*)(Pb + off);
      S.x = S.x*d64 + p.x; S.y = S.y*d64 + p.y;
      S.z = S.z*d64 + p.z; S.w = S.w*d64 + p.w;
    }
    if (part == 0 && tid < 64){
      float z = 0.f;
      for (int c=0;c<NCHUNK;c++){
        int zoff = (bh2*NCHUNK + c)*64 + tid;
        zprev[zoff] = f2b(z);
        z = z*d64 + zPb[zoff];
      }
    }
  }
  __threadfence();
  grid.sync();

  // ================= phase C: cross-chunk combine =================
  {
    unsigned short* Qb = sm_u;              // still valid from phase A (same block)
    unsigned short* Sp = sm_u + 64*PQ;      // [e][d]; row64 = zprev; 65..79 = 0
    #pragma unroll
    for (int i=0;i<2;i++){
      int g = tid + i*256;
      int r = g >> 3, c8 = (g & 7)*8;
      *(short8*)(Sp + r*PQ + c8) = *(const short8*)(Sprev + (size_t)bid*4096 + r*64 + c8);
    }
    if (tid < 64) Sp[64*PQ + tid] = zprev[bid*64 + tid];
    for (int i = tid; i < 15*PQ; i += 256) Sp[65*PQ + i] = 0;
    __syncthreads();

    f32x4 acc[5];
    #pragma unroll
    for (int et=0;et<5;et++) acc[et] = (f32x4){0.f,0.f,0.f,0.f};
    #pragma unroll
    for (int et=0;et<5;et++)
      #pragma unroll
      for (int ks=0;ks<2;ks++){
        short8 a = *(const short8*)(Qb + (w*16 + m16)*PQ + ks*32 + quad*8);
        short8 bv = *(const short8*)(Sp + (et*16 + m16)*PQ + ks*32 + quad*8);
        acc[et] = __builtin_amdgcn_mfma_f32_16x16x32_bf16(a, bv, acc[et], 0, 0, 0);
      }
    int trow = w*16 + quad*4;
    if (m16 == 0){
      #pragma unroll
      for (int r=0;r<4;r++){
        int tl = trow + r;
        float pw = exp2f((float)(tl+1)*l2d);
        float den = fmaxf(denb[bh*SEQ + chunk*64 + tl] + pw*acc[4][r], 1e-5f);
        den_sm[tl] = 1.f/den;
      }
    }
    __syncthreads();
    #pragma unroll
    for (int r=0;r<4;r++){
      int tl = trow + r;
      float pw = exp2f((float)(tl+1)*l2d);
      float invden = den_sm[tl];
      int tg = chunk*64 + tl;
      #pragma unroll
      for (int et=0;et<4;et++){
        int e = et*16 + m16;
        float nm = numb[base + (size_t)tl*64 + e] + pw*acc[et][r];
        attn[((size_t)(b*SEQ + tg))*D_MODEL + h*64 + e] = nm*invden;
      }
    }
  }
  __threadfence();
  grid.sync();

  // ================= phase D: memnorm -> bf16 =================
  for (int row = bid; row < NROWS; row += NATTN){
    const float* xr = attn + (size_t)row*D_MODEL;
    float v0 = xr[tid], v1 = xr[tid+256], v2 = xr[tid+512];
    float s = v0*v0 + v1*v1 + v2*v2;
    #pragma unroll
    for (int off=32; off; off>>=1) s += __shfl_xor(s, off, 64);
    if ((tid & 63) == 0) red[tid>>6] = s;
    __syncthreads();
    s = red[0]+red[1]+red[2]+red[3];
    float sc = rsqrtf(s*(1.f/(float)D_MODEL) + 1e-6f);
    unsigned short* yr = memn + (size_t)row*D_MODEL;
    yr[tid]     = f2b(v0*sc*w_mn[tid]);
    yr[tid+256] = f2b(v1*sc*w_mn[tid+256]);
    yr[tid+512] = f2b(v2*sc*w_mn[tid+512]);
    __syncthreads();
  }
}

extern "C" void kernel_launch(void* const* d_in, const int* in_sizes, int n_in,
                              void* d_out, int out_size, void* d_ws, size_t ws_size,
                              hipStream_t stream)
{
  (void)in_sizes; (void)n_in; (void)out_size; (void)ws_size;
  const float* x       = (const float*)d_in[0];
  const float* w_ln    = (const float*)d_in[1];
  const float* w_comp  = (const float*)d_in[2];
  const float* w_qkv   = (const float*)d_in[3];
  const float* w_reso  = (const float*)d_in[4];
  const float* w_qn    = (const float*)d_in[5];
  const float* w_kn    = (const float*)d_in[6];
  const float* hdec    = (const float*)d_in[7];
  const float* temp    = (const float*)d_in[8];
  const float* w_ogate = (const float*)d_in[9];
  const float* w_proj  = (const float*)d_in[10];
  const float* w_mn    = (const float*)d_in[11];
  float* ws = (float*)d_ws;
  float* out = (float*)d_out;

  // fp32 region (floats)
  const size_t o_cKV    = 0;
  const size_t o_cG     = o_cKV    + (size_t)NBH*SEQ;
  const size_t o_den    = o_cG     + (size_t)NBH*SEQ;
  const size_t o_P      = o_den    + (size_t)NBH*SEQ;          // 24*16*4096 ([e][d])
  const size_t o_zP     = o_P      + (size_t)NBH*NCHUNK*4096;
  const size_t o_attn   = o_zP     + (size_t)NBH*NCHUNK*64;
  const size_t o_numb   = o_attn   + (size_t)NROWS*D_MODEL;
  const size_t o_end    = o_numb   + (size_t)NBH*SEQ*64;

  // bf16 region (ushorts)
  unsigned short* bws = (unsigned short*)(ws + o_end);
  const size_t u_xn     = 0;
  const size_t u_latent = u_xn     + (size_t)NROWS*D_MODEL;
  const size_t u_memn   = u_latent + (size_t)NROWS*LATD;
  const size_t u_q      = u_memn   + (size_t)NROWS*D_MODEL;
  const size_t u_k      = u_q      + (size_t)NBH*SEQ*64;
  const size_t u_v      = u_k      + (size_t)NBH*SEQ*64;
  const size_t u_gate   = u_v      + (size_t)NBH*SEQ*64;       // 2048*768
  const size_t u_S      = u_gate   + (size_t)NROWS*D_MODEL;    // bf16 Sprev
  const size_t u_zprev  = u_S      + (size_t)NBH*NCHUNK*4096;
  const size_t u_wtc    = u_zprev  + (size_t)NBH*NCHUNK*64;
  const size_t u_wtq    = u_wtc    + (size_t)LATD*D_MODEL;     // 2432*512, wtg follows
  const size_t u_wtg    = u_wtq    + (size_t)2432*LATD;        // fused BT rows 2432..3199
  const size_t u_wtp    = u_wtg    + (size_t)D_MODEL*LATD;

  // 1. weight converts + xn rmsnorm (one launch)
  k_cvt_all<<<2688, 256, 0, stream>>>(w_comp, w_qkv, w_reso, w_ogate, w_proj,
      x, w_ln, bws + u_wtc, bws + u_wtq, bws + u_wtg, bws + u_wtp, bws + u_xn);
  // 2. latent = silu(xn @ w_compress) -> bf16  (BN=64: 128 blocks)
  k_mfma_gemm<<<dim3(LATD/64, NROWS/128), 256, 0, stream>>>(bws + u_xn, bws + u_wtc,
      nullptr, bws + u_latent, nullptr, NROWS, LATD, D_MODEL, 1);
  // 3. fused qkv+coef+gate GEMM with feat epilogue (400 blocks)
  k_gemm_fused<<<dim3(NFUSE/128, NROWS/128), 256, 0, stream>>>(bws + u_latent, bws + u_wtq,
      w_qn, w_kn, hdec, temp, bws + u_q, bws + u_k, bws + u_v,
      ws + o_cKV, ws + o_cG, bws + u_gate);
  // 4. cooperative attention megakernel (384 blocks, 4 phases)
  {
    const unsigned short* a_qf = bws + u_q;
    const unsigned short* a_kf = bws + u_k;
    const unsigned short* a_vf = bws + u_v;
    const float* a_cKV = ws + o_cKV;
    const float* a_cG  = ws + o_cG;
    const float* a_hd  = hdec;
    float* a_numb = ws + o_numb;
    float* a_den  = ws + o_den;
    float* a_P    = ws + o_P;
    float* a_zP   = ws + o_zP;
    unsigned short* a_S  = bws + u_S;
    unsigned short* a_zp = bws + u_zprev;
    float* a_attn = ws + o_attn;
    const float* a_wmn = w_mn;
    unsigned short* a_memn = bws + u_memn;
    void* kargs[] = { &a_qf, &a_kf, &a_vf, &a_cKV, &a_cG, &a_hd, &a_numb, &a_den,
                      &a_P, &a_zP, &a_S, &a_zp, &a_attn, &a_wmn, &a_memn };
    hipLaunchCooperativeKernel((const void*)k_attn, dim3(NATTN), dim3(256),
                               kargs, 0, stream);
  }
  // 5. out = (memn @ w_proj) * gate  (BN=64: 192 blocks)
  k_mfma_gemm<<<dim3(D_MODEL/64, NROWS/128), 256, 0, stream>>>(bws + u_memn, bws + u_wtp,
      out, nullptr, bws + u_gate, NROWS, D_MODEL, D_MODEL, 2);
}

// Round 6
// 244.631 us; speedup vs baseline: 2.1237x; 2.1237x over previous
//
#include <hip/hip_runtime.h>
#include <hip/hip_bf16.h>
#include <math.h>

// Problem constants (B=2, L=1024, D=768, H=12, DH=64, LAT=512)
#define D_MODEL 768
#define NHEAD   12
#define LATD    512
#define BATCH   2
#define SEQ     1024
#define NROWS   (BATCH*SEQ)          // 2048
#define NCHUNK  (SEQ/64)             // 16
#define NBH     (BATCH*NHEAD)        // 24
#define NFUSE   3200                 // qkv 2304 + params pad 128 + gate 768
#define PQ      72                   // LDS ushort pitch (144 B rows, 16B-aligned frags)

using short8 = __attribute__((ext_vector_type(8))) short;
using f32x4  = __attribute__((ext_vector_type(4))) float;

__device__ __forceinline__ float sigf(float x){ return 1.f/(1.f+expf(-x)); }
__device__ __forceinline__ float decay_of(float hd){
  float d = 0.3f + 0.65f*sigf(hd);
  return fminf(fmaxf(d, 1e-5f), 0.999f);
}
__device__ __forceinline__ unsigned short f2b(float f){
  __hip_bfloat16 h = __float2bfloat16(f);
  return *reinterpret_cast<unsigned short*>(&h);
}
__device__ __forceinline__ float bf2f(unsigned short u){
  unsigned int x = ((unsigned int)u) << 16;
  return __uint_as_float(x);
}
__device__ __forceinline__ void async16(const unsigned short* g, unsigned short* l){
  __builtin_amdgcn_global_load_lds((const __attribute__((address_space(1))) void*)g,
                                   (__attribute__((address_space(3))) void*)l, 16, 0, 0);
}

// ---------------- rmsnorm over D=768 -> bf16 out, one block per row ----------------
__global__ __launch_bounds__(256) void k_rmsnorm_bf(const float* __restrict__ x,
    const float* __restrict__ w, unsigned short* __restrict__ y)
{
  int row = blockIdx.x, tid = threadIdx.x;
  const float* xr = x + (size_t)row*D_MODEL;
  float v0 = xr[tid], v1 = xr[tid+256], v2 = xr[tid+512];
  float s = v0*v0 + v1*v1 + v2*v2;
  #pragma unroll
  for (int off=32; off; off>>=1) s += __shfl_xor(s, off, 64);
  __shared__ float red[4];
  if ((tid & 63) == 0) red[tid>>6] = s;
  __syncthreads();
  s = red[0]+red[1]+red[2]+red[3];
  float sc = rsqrtf(s*(1.f/(float)D_MODEL) + 1e-6f);
  unsigned short* yr = y + (size_t)row*D_MODEL;
  yr[tid]     = f2b(v0*sc*w[tid]);
  yr[tid+256] = f2b(v1*sc*w[tid+256]);
  yr[tid+512] = f2b(v2*sc*w[tid+512]);
}

// ------- weight converts/transposes + xn rmsnorm, one launch (2688 blocks) -------
__global__ __launch_bounds__(256) void k_cvt_all(const float* __restrict__ wc,
    const float* __restrict__ wq, const float* __restrict__ wr,
    const float* __restrict__ wg, const float* __restrict__ wp,
    const float* __restrict__ x, const float* __restrict__ wln,
    unsigned short* __restrict__ wtc, unsigned short* __restrict__ wtq,
    unsigned short* __restrict__ wtg, unsigned short* __restrict__ wtp,
    unsigned short* __restrict__ xn)
{
  __shared__ unsigned short tile[64][65];
  __shared__ float red[4];
  int blk = blockIdx.x, t = threadIdx.x;
  if (blk >= 640){
    // rmsnorm(x) -> bf16 xn, one block per row
    int row = blk - 640;
    const float* xr = x + (size_t)row*D_MODEL;
    float v0 = xr[t], v1 = xr[t+256], v2 = xr[t+512];
    float s = v0*v0 + v1*v1 + v2*v2;
    #pragma unroll
    for (int off=32; off; off>>=1) s += __shfl_xor(s, off, 64);
    if ((t & 63) == 0) red[t>>6] = s;
    __syncthreads();
    s = red[0]+red[1]+red[2]+red[3];
    float sc = rsqrtf(s*(1.f/(float)D_MODEL) + 1e-6f);
    unsigned short* yr = xn + (size_t)row*D_MODEL;
    yr[t]     = f2b(v0*sc*wln[t]);
    yr[t+256] = f2b(v1*sc*wln[t+256]);
    yr[t+512] = f2b(v2*sc*wln[t+512]);
    return;
  }
  if (blk >= 624){
    // w_reso [512][48] -> wtq rows 2304..2431 (zero-pad 2352..2431)
    int i = blk - 624;                    // 0..15
    #pragma unroll
    for (int j=0;j<16;j++){
      int e = i*4096 + t + j*256;         // 0..65535
      int n = 2304 + (e >> 9), k = e & 511;
      float v = (n < 2352) ? wr[(size_t)k*48 + (n-2304)] : 0.f;
      wtq[(size_t)n*512 + k] = f2b(v);
    }
    return;
  }
  const float* W; unsigned short* WT; int K, N, bx, by;
  if (blk < 96){ W=wc; WT=wtc; K=768; N=512; bx=blk&7; by=blk>>3; }
  else if (blk < 384){ int i=blk-96;  W=wq; WT=wtq; K=512; N=2304; bx=i%36; by=i/36; }
  else if (blk < 480){ int i=blk-384; W=wg; WT=wtg; K=512; N=768;  bx=i%12; by=i/12; }
  else               { int i=blk-480; W=wp; WT=wtp; K=768; N=768;  bx=i%12; by=i/12; }
  int k0 = by*64, n0 = bx*64, cr = t >> 6, cc = t & 63;
  #pragma unroll
  for (int i=0;i<16;i++){
    int r = cr + i*4;
    tile[r][cc] = f2b(W[(size_t)(k0+r)*N + n0 + cc]);
  }
  __syncthreads();
  #pragma unroll
  for (int i=0;i<16;i++){
    int nn = cr + i*4;
    WT[(size_t)(n0+nn)*K + k0 + cc] = tile[cc][nn];
  }
}

// ------- bf16 MFMA GEMM, BM=128 BN=64: C = A[M,K] @ BT[N,K]^T -------------------
// act: 1 = silu (bf16 out Cb), 2 = multiply by bf16 aux (fp32 out Cf)
__global__ __launch_bounds__(256) void k_mfma_gemm(const unsigned short* __restrict__ A,
    const unsigned short* __restrict__ BT, float* __restrict__ Cf,
    unsigned short* __restrict__ Cb, const unsigned short* __restrict__ auxb,
    int M, int N, int K, int act)
{
  __shared__ unsigned short As[128*64];
  __shared__ unsigned short Bs[64*64];
  int tid = threadIdx.x;
  int w = tid >> 6, lane = tid & 63;
  int wm = (w >> 1)*64, wn = (w & 1)*32;
  int m16 = lane & 15, quad = lane >> 4;
  int bm = blockIdx.y*128, bn = blockIdx.x*64;

  f32x4 acc[4][2];
  #pragma unroll
  for (int i=0;i<4;i++)
    #pragma unroll
    for (int j=0;j<2;j++) acc[i][j] = (f32x4){0.f,0.f,0.f,0.f};

  for (int kk = 0; kk < K; kk += 64){
    #pragma unroll
    for (int i=0;i<4;i++){
      int g = (w*4 + i)*64 + lane;
      int m = g >> 3, c = (g & 7) ^ (m & 7);
      async16(A + (size_t)(bm+m)*K + kk + c*8, As + (w*4+i)*512);
    }
    #pragma unroll
    for (int i=0;i<2;i++){
      int g = (w*2 + i)*64 + lane;
      int m = g >> 3, c = (g & 7) ^ (m & 7);
      async16(BT + (size_t)(bn+m)*K + kk + c*8, Bs + (w*2+i)*512);
    }
    __syncthreads();
    #pragma unroll
    for (int s=0;s<2;s++){
      short8 af[4], bf[2];
      #pragma unroll
      for (int mt=0;mt<4;mt++){
        int m = wm + mt*16 + m16;
        int idx = m*8 + ((s*4 + quad) ^ (m & 7));
        af[mt] = *(const short8*)(As + idx*8);
      }
      #pragma unroll
      for (int nt=0;nt<2;nt++){
        int n = wn + nt*16 + m16;
        int idx = n*8 + ((s*4 + quad) ^ (n & 7));
        bf[nt] = *(const short8*)(Bs + idx*8);
      }
      #pragma unroll
      for (int mt=0;mt<4;mt++)
        #pragma unroll
        for (int nt=0;nt<2;nt++)
          acc[mt][nt] = __builtin_amdgcn_mfma_f32_16x16x32_bf16(af[mt], bf[nt], acc[mt][nt], 0, 0, 0);
    }
    __syncthreads();
  }
  #pragma unroll
  for (int mt=0;mt<4;mt++){
    #pragma unroll
    for (int r=0;r<4;r++){
      int row = bm + wm + mt*16 + quad*4 + r;
      #pragma unroll
      for (int nt=0;nt<2;nt++){
        int col = bn + wn + nt*16 + m16;
        float v = acc[mt][nt][r];
        if (act == 1) v = v/(1.f + __expf(-v));
        else if (act == 2) v *= bf2f(auxb[(size_t)row*N + col]);
        if (Cf) Cf[(size_t)row*N + col] = v;
        if (Cb) Cb[(size_t)row*N + col] = f2b(v);
      }
    }
  }
}

// ------- fused GEMM: [qkv | params | gate] = latent @ BT (N=3200) ----------------
// Epilogue: per-head rmsnorm + rope + elu+1 (q/k), v copy, coef (params), silu gate.
__global__ __launch_bounds__(256) void k_gemm_fused(const unsigned short* __restrict__ A,
    const unsigned short* __restrict__ BT, const float* __restrict__ w_qn,
    const float* __restrict__ w_kn, const float* __restrict__ hdec,
    const float* __restrict__ temp, unsigned short* __restrict__ qf,
    unsigned short* __restrict__ kf, unsigned short* __restrict__ vf,
    float* __restrict__ cKV, float* __restrict__ cG,
    unsigned short* __restrict__ gateb)
{
  __shared__ unsigned short As[128*64];
  __shared__ unsigned short Bs[128*64];
  const int K = LATD;
  int tid = threadIdx.x;
  int w = tid >> 6, lane = tid & 63;
  int wm = (w >> 1)*64, wn = (w & 1)*64;
  int m16 = lane & 15, quad = lane >> 4;
  int bm = blockIdx.y*128, bn = blockIdx.x*128;

  f32x4 acc[4][4];
  #pragma unroll
  for (int i=0;i<4;i++)
    #pragma unroll
    for (int j=0;j<4;j++) acc[i][j] = (f32x4){0.f,0.f,0.f,0.f};

  for (int kk = 0; kk < K; kk += 64){
    #pragma unroll
    for (int i=0;i<4;i++){
      int g = (w*4 + i)*64 + lane;
      int m = g >> 3, c = (g & 7) ^ (m & 7);
      async16(A  + (size_t)(bm+m)*K + kk + c*8, As + (w*4+i)*512);
      async16(BT + (size_t)(bn+m)*K + kk + c*8, Bs + (w*4+i)*512);
    }
    __syncthreads();
    #pragma unroll
    for (int s=0;s<2;s++){
      short8 af[4], bf[4];
      #pragma unroll
      for (int mt=0;mt<4;mt++){
        int m = wm + mt*16 + m16;
        int idx = m*8 + ((s*4 + quad) ^ (m & 7));
        af[mt] = *(const short8*)(As + idx*8);
      }
      #pragma unroll
      for (int nt=0;nt<4;nt++){
        int n = wn + nt*16 + m16;
        int idx = n*8 + ((s*4 + quad) ^ (n & 7));
        bf[nt] = *(const short8*)(Bs + idx*8);
      }
      #pragma unroll
      for (int mt=0;mt<4;mt++)
        #pragma unroll
        for (int nt=0;nt<4;nt++)
          acc[mt][nt] = __builtin_amdgcn_mfma_f32_16x16x32_bf16(af[mt], bf[nt], acc[mt][nt], 0, 0, 0);
    }
    __syncthreads();
  }

  int colbase = bn + wn;                // 64-aligned; wave owns cols [colbase, colbase+64)
  if (colbase < 2304){
    int sec = colbase >= 1536 ? 2 : (colbase >= 768 ? 1 : 0);   // 0=q 1=k 2=v
    int h = (colbase - sec*768) >> 6;
    if (sec == 2){
      #pragma unroll
      for (int mt=0;mt<4;mt++)
        #pragma unroll
        for (int r=0;r<4;r++){
          int row = bm + wm + mt*16 + quad*4 + r;
          int b = row >> 10, t = row & 1023;
          size_t ob = (((size_t)(b*NHEAD+h))*SEQ + t)*64;
          #pragma unroll
          for (int nt=0;nt<4;nt++)
            vf[ob + nt*16 + m16] = f2b(acc[mt][nt][r]);
        }
    } else {
      const float* wnp = sec ? w_kn : w_qn;
      unsigned short* of = sec ? kf : qf;
      float wv4[4];
      #pragma unroll
      for (int nt=0;nt<4;nt++) wv4[nt] = wnp[nt*16 + m16];
      float inv0 = exp2f(-(float)m16*(1.f/32.f)*13.28771237954945f);  // 10000^{-m16/32}
      float inv1 = inv0 * 0.01f;                                      // * 10000^{-16/32}
      #pragma unroll
      for (int mt=0;mt<4;mt++)
        #pragma unroll
        for (int r=0;r<4;r++){
          int row = bm + wm + mt*16 + quad*4 + r;
          int b = row >> 10, t = row & 1023;
          float s = 0.f;
          #pragma unroll
          for (int nt=0;nt<4;nt++) s += acc[mt][nt][r]*acc[mt][nt][r];
          s += __shfl_xor(s, 1, 64); s += __shfl_xor(s, 2, 64);
          s += __shfl_xor(s, 4, 64); s += __shfl_xor(s, 8, 64);
          float rs = rsqrtf(s*(1.f/64.f) + 1e-6f);
          float qv[4];
          #pragma unroll
          for (int nt=0;nt<4;nt++) qv[nt] = acc[mt][nt][r]*rs*wv4[nt];
          float s0,c0,s1,c1;
          __sincosf((float)t*inv0, &s0, &c0);
          __sincosf((float)t*inv1, &s1, &c1);
          size_t ob = (((size_t)(b*NHEAD+h))*SEQ + t)*64;
          #pragma unroll
          for (int nt=0;nt<4;nt++){
            float rot = (nt < 2) ? -qv[nt+2] : qv[nt-2];
            float cs = (nt & 1) ? c1 : c0, sn = (nt & 1) ? s1 : s0;
            float val = qv[nt]*cs + rot*sn;
            val = (val > 0.f) ? val + 1.f : __expf(val);
            of[ob + nt*16 + m16] = f2b(val);
          }
        }
    }
  } else if (colbase == 2304){
    // resonance params -> coefficients (head h = p>>2, param pi = p&3 in lane m16)
    float temp0 = temp[0];
    #pragma unroll
    for (int mt=0;mt<4;mt++)
      #pragma unroll
      for (int r=0;r<4;r++){
        int row = bm + wm + mt*16 + quad*4 + r;
        int b = row >> 10, t = row & 1023;
        #pragma unroll
        for (int nt=0;nt<3;nt++){
          int p = nt*16 + m16, h2 = p >> 2, pi = p & 3;
          float v  = acc[mt][nt][r];
          float v1 = __shfl_xor(v, 1, 64);
          float v2 = __shfl_xor(v, 2, 64);
          float v3 = __shfl_xor(v, 3, 64);
          if (pi == 0){
            float sa = sigf(v);
            float sp = sigf(v1)*3.14159265358979323846f;
            float ca = sigf(v2);
            float cp = sigf(v3)*3.14159265358979323846f;
            float z = sa*ca*cosf(sp - cp)*temp0;
            float gate = fminf(fmaxf(sigf(z)*1.2f - 0.1f, 0.05f), 0.95f);
            float dd = decay_of(hdec[h2]);
            float df = expf((float)(t+1)*logf(dd));
            float g = df/(df + 1e-8f);
            int ci = (b*NHEAD + h2)*SEQ + t;
            cKV[ci] = g*gate*(1.f - dd);
            cG[ci]  = 1.f/gate;
          }
        }
      }
  } else if (colbase >= 2432){
    // out-gate: silu -> bf16
    #pragma unroll
    for (int mt=0;mt<4;mt++)
      #pragma unroll
      for (int r=0;r<4;r++){
        int row = bm + wm + mt*16 + quad*4 + r;
        #pragma unroll
        for (int nt=0;nt<4;nt++){
          int gc = colbase + nt*16 + m16 - 2432;
          float v = acc[mt][nt][r];
          v = v/(1.f + __expf(-v));
          gateb[(size_t)row*D_MODEL + gc] = f2b(v);
        }
      }
  }
}

// ---------------- intra-chunk: MFMA scores + num/den + P^T/zP ----------------
__global__ __launch_bounds__(256) void k_intra(const unsigned short* __restrict__ qf,
    const unsigned short* __restrict__ kf, const unsigned short* __restrict__ vf,
    const float* __restrict__ cKVb, const float* __restrict__ cGb,
    const float* __restrict__ hdec, float* __restrict__ numb,
    float* __restrict__ denb, float* __restrict__ Pb, float* __restrict__ zPb)
{
  __shared__ __align__(16) unsigned short Qb[64*PQ];   // Q_f  [t][k]
  __shared__ __align__(16) unsigned short Kb[64*PQ];   // K_f  [s][d]
  __shared__ __align__(16) unsigned short KtS[64*PQ];  // (K_f*cps)^T [d][s]
  __shared__ __align__(16) unsigned short Wb[64*PQ];   // Wn   [t][s]
  __shared__ __align__(16) unsigned short Vt[80*PQ];   // V^T  [e][s]; row64 = invgate; 65..79 = 0
  __shared__ float cn[64], cps[64];
  int bid = blockIdx.x;
  int chunk = bid & 15, bh = bid >> 4, h = bh % NHEAD;
  int tid = threadIdx.x, w = tid >> 6, lane = tid & 63;
  int m16 = lane & 15, quad = lane >> 4;
  size_t base = ((size_t)bh*SEQ + chunk*64)*64;
  float d = decay_of(hdec[h]);
  float l2d = log2f(d);

  if (tid < 64){
    float c = cKVb[bh*SEQ + chunk*64 + tid];
    float pw = exp2f((float)(63 - tid)*l2d);
    cn[tid] = c;
    cps[tid] = c*pw;
    Vt[64*PQ + tid] = f2b(cGb[bh*SEQ + chunk*64 + tid]);
  }
  for (int i = tid; i < 15*PQ; i += 256) Vt[65*PQ + i] = 0;
  __syncthreads();   // cps ready for KtS staging

  #pragma unroll
  for (int i=0;i<2;i++){
    int g = tid + i*256;
    int r = g >> 3, c8 = (g & 7)*8;
    *(short8*)(Qb + r*PQ + c8) = *(const short8*)(qf + base + r*64 + c8);
    *(short8*)(Kb + r*PQ + c8) = *(const short8*)(kf + base + r*64 + c8);
  }
  {
    int s = tid & 63;
    float cpss = cps[s];
    #pragma unroll
    for (int i=0;i<2;i++){
      int c8 = ((tid >> 6) + i*4)*8;
      short8 vv = *(const short8*)(vf + base + s*64 + c8);
      short8 kk = *(const short8*)(kf + base + s*64 + c8);
      #pragma unroll
      for (int j=0;j<8;j++){
        Vt[(c8+j)*PQ + s] = ((unsigned short*)&vv)[j];
        KtS[(c8+j)*PQ + s] = f2b(bf2f(((unsigned short*)&kk)[j])*cpss);
      }
    }
  }
  __syncthreads();

  int trow = w*16 + quad*4;
  for (int stile=0; stile<4; stile++){
    if (stile > w){
      #pragma unroll
      for (int r=0;r<4;r++) Wb[(trow+r)*PQ + stile*16 + m16] = 0;
      continue;
    }
    f32x4 acc = (f32x4){0.f,0.f,0.f,0.f};
    #pragma unroll
    for (int ks=0;ks<2;ks++){
      short8 a = *(const short8*)(Qb + (w*16 + m16)*PQ + ks*32 + quad*8);
      short8 bv = *(const short8*)(Kb + (stile*16 + m16)*PQ + ks*32 + quad*8);
      acc = __builtin_amdgcn_mfma_f32_16x16x32_bf16(a, bv, acc, 0, 0, 0);
    }
    int s = stile*16 + m16;
    float cns = cn[s];
    #pragma unroll
    for (int r=0;r<4;r++){
      int t = trow + r;
      float wv = 0.f;
      if (s <= t) wv = acc[r]*exp2f((float)(t-s)*l2d)*cns;
      Wb[t*PQ + s] = f2b(wv);
    }
  }
  __syncthreads();

  {
    f32x4 acc[5];
    #pragma unroll
    for (int et=0;et<5;et++) acc[et] = (f32x4){0.f,0.f,0.f,0.f};
    #pragma unroll
    for (int et=0;et<5;et++)
      #pragma unroll
      for (int ks=0;ks<2;ks++){
        short8 a = *(const short8*)(Wb + (w*16 + m16)*PQ + ks*32 + quad*8);
        short8 bv = *(const short8*)(Vt + (et*16 + m16)*PQ + ks*32 + quad*8);
        acc[et] = __builtin_amdgcn_mfma_f32_16x16x32_bf16(a, bv, acc[et], 0, 0, 0);
      }
    #pragma unroll
    for (int et=0;et<4;et++)
      #pragma unroll
      for (int r=0;r<4;r++)
        numb[base + (size_t)(trow+r)*64 + et*16 + m16] = acc[et][r];
    if (m16 == 0){
      #pragma unroll
      for (int r=0;r<4;r++)
        denb[bh*SEQ + chunk*64 + trow + r] = acc[4][r];
    }
  }
  {
    #pragma unroll
    for (int j=0;j<5;j++){
      int tIdx = w + 4*j;
      int et = tIdx >> 2, dt = tIdx & 3;
      f32x4 acc = (f32x4){0.f,0.f,0.f,0.f};
      #pragma unroll
      for (int ks=0;ks<2;ks++){
        short8 a = *(const short8*)(Vt  + (et*16 + m16)*PQ + ks*32 + quad*8);
        short8 bv = *(const short8*)(KtS + (dt*16 + m16)*PQ + ks*32 + quad*8);
        acc = __builtin_amdgcn_mfma_f32_16x16x32_bf16(a, bv, acc, 0, 0, 0);
      }
      if (et < 4){
        #pragma unroll
        for (int r=0;r<4;r++)
          Pb[(size_t)bid*4096 + (et*16 + quad*4 + r)*64 + dt*16 + m16] = acc[r];
      } else {
        if (quad == 0) zPb[bid*64 + dt*16 + m16] = acc[0];
      }
    }
  }
}

// ---------------- chunk-level state scan -> bf16 Sprev/zprev ----------------
__global__ __launch_bounds__(256) void k_scan(const float* __restrict__ Pb,
    const float* __restrict__ zPb, unsigned short* __restrict__ Sprev,
    unsigned short* __restrict__ zprev, const float* __restrict__ hdec)
{
  int bh = blockIdx.x >> 2, part = blockIdx.x & 3;
  int h = bh % NHEAD, tid = threadIdx.x;
  float d = decay_of(hdec[h]);
  float d64 = exp2f(64.f*log2f(d));
  int idx = part*1024 + tid*4;
  float4 S = make_float4(0.f,0.f,0.f,0.f);
  for (int c=0;c<NCHUNK;c++){
    size_t off = ((size_t)bh*NCHUNK + c)*4096 + idx;
    unsigned int lo = (unsigned int)f2b(S.x) | ((unsigned int)f2b(S.y) << 16);
    unsigned int hi = (unsigned int)f2b(S.z) | ((unsigned int)f2b(S.w) << 16);
    *(uint2*)(Sprev + off) = make_uint2(lo, hi);
    float4 p = *(const float4*)(Pb + off);
    S.x = S.x*d64 + p.x; S.y = S.y*d64 + p.y;
    S.z = S.z*d64 + p.z; S.w = S.w*d64 + p.w;
  }
  if (part == 0 && tid < 64){
    float z = 0.f;
    for (int c=0;c<NCHUNK;c++){
      int zoff = (bh*NCHUNK + c)*64 + tid;
      zprev[zoff] = f2b(z);
      z = z*d64 + zPb[zoff];
    }
  }
}

// ---------------- cross-chunk combine via MFMA + final attention out ----------------
__global__ __launch_bounds__(256) void k_cross(const unsigned short* __restrict__ qf,
    const unsigned short* __restrict__ Sprev, const unsigned short* __restrict__ zprev,
    const float* __restrict__ numb, const float* __restrict__ denb,
    const float* __restrict__ hdec, float* __restrict__ attn)
{
  __shared__ __align__(16) unsigned short Qb[64*PQ];   // Q_f [t][k]
  __shared__ __align__(16) unsigned short Sp[80*PQ];   // S [e][d]; row64 = zprev; 65..79 = 0
  __shared__ float den_sm[64];
  int bid = blockIdx.x;
  int chunk = bid & 15, bh = bid >> 4, h = bh % NHEAD, b = bh / NHEAD;
  int tid = threadIdx.x, w = tid >> 6, lane = tid & 63;
  int m16 = lane & 15, quad = lane >> 4;
  size_t base = ((size_t)bh*SEQ + chunk*64)*64;
  float d = decay_of(hdec[h]);
  float l2d = log2f(d);

  #pragma unroll
  for (int i=0;i<2;i++){
    int g = tid + i*256;
    int r = g >> 3, c8 = (g & 7)*8;
    *(short8*)(Qb + r*PQ + c8) = *(const short8*)(qf + base + r*64 + c8);
    *(short8*)(Sp + r*PQ + c8) = *(const short8*)(Sprev + (size_t)bid*4096 + r*64 + c8);
  }
  if (tid < 64) Sp[64*PQ + tid] = zprev[bid*64 + tid];
  for (int i = tid; i < 15*PQ; i += 256) Sp[65*PQ + i] = 0;
  __syncthreads();

  f32x4 acc[5];
  #pragma unroll
  for (int et=0;et<5;et++) acc[et] = (f32x4){0.f,0.f,0.f,0.f};
  #pragma unroll
  for (int et=0;et<5;et++)
    #pragma unroll
    for (int ks=0;ks<2;ks++){
      short8 a = *(const short8*)(Qb + (w*16 + m16)*PQ + ks*32 + quad*8);
      short8 bv = *(const short8*)(Sp + (et*16 + m16)*PQ + ks*32 + quad*8);
      acc[et] = __builtin_amdgcn_mfma_f32_16x16x32_bf16(a, bv, acc[et], 0, 0, 0);
    }
  int trow = w*16 + quad*4;
  if (m16 == 0){
    #pragma unroll
    for (int r=0;r<4;r++){
      int tl = trow + r;
      float pw = exp2f((float)(tl+1)*l2d);
      float den = fmaxf(denb[bh*SEQ + chunk*64 + tl] + pw*acc[4][r], 1e-5f);
      den_sm[tl] = 1.f/den;
    }
  }
  __syncthreads();
  #pragma unroll
  for (int r=0;r<4;r++){
    int tl = trow + r;
    float pw = exp2f((float)(tl+1)*l2d);
    float invden = den_sm[tl];
    int tg = chunk*64 + tl;
    #pragma unroll
    for (int et=0;et<4;et++){
      int e = et*16 + m16;
      float nm = numb[base + (size_t)tl*64 + e] + pw*acc[et][r];
      attn[((size_t)(b*SEQ + tg))*D_MODEL + h*64 + e] = nm*invden;
    }
  }
}

extern "C" void kernel_launch(void* const* d_in, const int* in_sizes, int n_in,
                              void* d_out, int out_size, void* d_ws, size_t ws_size,
                              hipStream_t stream)
{
  (void)in_sizes; (void)n_in; (void)out_size; (void)ws_size;
  const float* x       = (const float*)d_in[0];
  const float* w_ln    = (const float*)d_in[1];
  const float* w_comp  = (const float*)d_in[2];
  const float* w_qkv   = (const float*)d_in[3];
  const float* w_reso  = (const float*)d_in[4];
  const float* w_qn    = (const float*)d_in[5];
  const float* w_kn    = (const float*)d_in[6];
  const float* hdec    = (const float*)d_in[7];
  const float* temp    = (const float*)d_in[8];
  const float* w_ogate = (const float*)d_in[9];
  const float* w_proj  = (const float*)d_in[10];
  const float* w_mn    = (const float*)d_in[11];
  float* ws = (float*)d_ws;
  float* out = (float*)d_out;

  // fp32 region (floats)
  const size_t o_cKV    = 0;
  const size_t o_cG     = o_cKV    + (size_t)NBH*SEQ;
  const size_t o_den    = o_cG     + (size_t)NBH*SEQ;
  const size_t o_P      = o_den    + (size_t)NBH*SEQ;          // 24*16*4096 ([e][d])
  const size_t o_zP     = o_P      + (size_t)NBH*NCHUNK*4096;
  const size_t o_attn   = o_zP     + (size_t)NBH*NCHUNK*64;
  const size_t o_numb   = o_attn   + (size_t)NROWS*D_MODEL;
  const size_t o_end    = o_numb   + (size_t)NBH*SEQ*64;

  // bf16 region (ushorts)
  unsigned short* bws = (unsigned short*)(ws + o_end);
  const size_t u_xn     = 0;
  const size_t u_latent = u_xn     + (size_t)NROWS*D_MODEL;
  const size_t u_memn   = u_latent + (size_t)NROWS*LATD;
  const size_t u_q      = u_memn   + (size_t)NROWS*D_MODEL;
  const size_t u_k      = u_q      + (size_t)NBH*SEQ*64;
  const size_t u_v      = u_k      + (size_t)NBH*SEQ*64;
  const size_t u_gate   = u_v      + (size_t)NBH*SEQ*64;       // 2048*768
  const size_t u_S      = u_gate   + (size_t)NROWS*D_MODEL;    // bf16 Sprev
  const size_t u_zprev  = u_S      + (size_t)NBH*NCHUNK*4096;
  const size_t u_wtc    = u_zprev  + (size_t)NBH*NCHUNK*64;
  const size_t u_wtq    = u_wtc    + (size_t)LATD*D_MODEL;     // 2432*512, wtg follows
  const size_t u_wtg    = u_wtq    + (size_t)2432*LATD;        // fused BT rows 2432..3199
  const size_t u_wtp    = u_wtg    + (size_t)D_MODEL*LATD;

  // 1. weight converts + xn rmsnorm (one launch)
  k_cvt_all<<<2688, 256, 0, stream>>>(w_comp, w_qkv, w_reso, w_ogate, w_proj,
      x, w_ln, bws + u_wtc, bws + u_wtq, bws + u_wtg, bws + u_wtp, bws + u_xn);
  // 2. latent = silu(xn @ w_compress) -> bf16  (BN=64: 128 blocks)
  k_mfma_gemm<<<dim3(LATD/64, NROWS/128), 256, 0, stream>>>(bws + u_xn, bws + u_wtc,
      nullptr, bws + u_latent, nullptr, NROWS, LATD, D_MODEL, 1);
  // 3. fused qkv+coef+gate GEMM with feat epilogue (400 blocks)
  k_gemm_fused<<<dim3(NFUSE/128, NROWS/128), 256, 0, stream>>>(bws + u_latent, bws + u_wtq,
      w_qn, w_kn, hdec, temp, bws + u_q, bws + u_k, bws + u_v,
      ws + o_cKV, ws + o_cG, bws + u_gate);
  // 4. intra-chunk (MFMA)
  k_intra<<<NBH*NCHUNK, 256, 0, stream>>>(bws + u_q, bws + u_k, bws + u_v,
      ws + o_cKV, ws + o_cG, hdec, ws + o_numb, ws + o_den, ws + o_P, ws + o_zP);
  // 5. chunk-level scan -> bf16 states
  k_scan<<<NBH*4, 256, 0, stream>>>(ws + o_P, ws + o_zP, bws + u_S, bws + u_zprev, hdec);
  // 6. cross-chunk combine (MFMA) -> attn fp32
  k_cross<<<NBH*NCHUNK, 256, 0, stream>>>(bws + u_q, bws + u_S, bws + u_zprev,
      ws + o_numb, ws + o_den, hdec, ws + o_attn);
  // 7. memnorm -> bf16
  k_rmsnorm_bf<<<NROWS, 256, 0, stream>>>(ws + o_attn, w_mn, bws + u_memn);
  // 8. out = (memn @ w_proj) * gate  (BN=64: 192 blocks)
  k_mfma_gemm<<<dim3(D_MODEL/64, NROWS/128), 256, 0, stream>>>(bws + u_memn, bws + u_wtp,
      out, nullptr, bws + u_gate, NROWS, D_MODEL, D_MODEL, 2);
}